// Round 3
// baseline (622.105 us; speedup 1.0000x reference)
//
#include <hip/hip_runtime.h>

#define EPS 1e-8f

constexpr int B = 16, C = 19, H = 512, W = 512;
constexpr int HW = H * W;               // 262144 = 2^18
constexpr int NPIX = B * HW;            // 4194304
constexpr long long NPRED = (long long)B * C * HW;  // 79691776

constexpr int GRID  = 1024;             // 4 blocks/CU resident (persistent)
constexpr int ITERS = NPIX / 4 / (GRID * 256);  // 4

typedef float f32x4 __attribute__((ext_vector_type(4)));

// ws layout (floats): [0..360] ncm (row-major [c][t]), [361..721] log(ncm+eps), [768] loss accumulator

__global__ void ncm_kernel(const float* __restrict__ cm, float* __restrict__ ws) {
    int t = threadIdx.x;
    if (t == 0) ws[768] = 0.0f;  // zero the loss accumulator (ws is poisoned each call)
    if (t < C) {
        float row[C];
        float m = -1e30f;
        #pragma unroll
        for (int j = 0; j < C; ++j) { row[j] = cm[t * C + j]; m = fmaxf(m, row[j]); }
        float s = 0.0f;
        #pragma unroll
        for (int j = 0; j < C; ++j) { row[j] = __expf(row[j] - m); s += row[j]; }
        float inv = 1.0f / s;
        #pragma unroll
        for (int j = 0; j < C; ++j) {
            float v = row[j] * inv;
            ws[t * C + j] = v;
            ws[361 + t * C + j] = __logf(v + EPS);
        }
    }
}

// Persistent grid-stride: 1024 blocks x 4 iterations x 4 px/thread.
// Loads CACHED (L3 held ~50% of logits across iterations in round 0 —
// NT loads in round 2 bypassed that and re-paid HBM). Stores NT (pred is
// written once, never re-read; keeps L3 clean for logits).
// Loss algebra (unnormalized accumulation, one log per pixel):
//   loss_pix = [sum_c ncm*e*(lpre + (x-m))] / [sum_c ncm*e] - log(s)
__global__ __launch_bounds__(256, 4) void emloss_main(
        const float* __restrict__ logits,
        const int* __restrict__ targets,
        const float* __restrict__ ws,
        float* __restrict__ pred,
        float* __restrict__ loss_acc) {
    __shared__ float s_ncm[C * C];
    __shared__ float s_lpre[C * C];
    __shared__ float s_red[4];
    for (int i = threadIdx.x; i < C * C; i += blockDim.x) {
        s_ncm[i]  = ws[i];
        s_lpre[i] = ws[361 + i];
    }
    __syncthreads();

    float lsum = 0.0f;

    for (int it = 0; it < ITERS; ++it) {
        int g = it * (GRID * 256) + blockIdx.x * 256 + threadIdx.x;
        int pbase = g * 4;
        int b = pbase >> 18;                             // / HW
        int r = pbase & (HW - 1);
        const float* lp = logits + (size_t)b * C * HW + r;
        float*       op = pred   + (size_t)b * C * HW + r;

        // 19 classes x 4 pixels, coalesced 16 B/lane cached loads
        f32x4 xs[C];
        #pragma unroll
        for (int c = 0; c < C; ++c)
            xs[c] = *(const f32x4*)(lp + (size_t)c * HW);
        int4 tv = *(const int4*)(targets + pbase);
        int tt[4] = {tv.x, tv.y, tv.z, tv.w};

        float m[4] = {-1e30f, -1e30f, -1e30f, -1e30f};
        #pragma unroll
        for (int c = 0; c < C; ++c) {
            #pragma unroll
            for (int k = 0; k < 4; ++k) m[k] = fmaxf(m[k], xs[c][k]);
        }

        // single fused pass: exp, softmax denom, loss numerator/denominator
        float s[4]     = {0, 0, 0, 0};
        float denom[4] = {0, 0, 0, 0};
        float acc[4]   = {0, 0, 0, 0};
        #pragma unroll
        for (int c = 0; c < C; ++c) {
            #pragma unroll
            for (int k = 0; k < 4; ++k) {
                float d = xs[c][k] - m[k];
                float e = __expf(d);
                s[k] += e;
                float num = s_ncm[c * C + tt[k]] * e;
                denom[k] += num;
                acc[k]   += num * (s_lpre[c * C + tt[k]] + d);
                xs[c][k] = e;   // keep unnormalized exp for pred store
            }
        }

        float inv[4];
        #pragma unroll
        for (int k = 0; k < 4; ++k) inv[k] = 1.0f / s[k];
        #pragma unroll
        for (int c = 0; c < C; ++c) {
            f32x4 pv = {xs[c][0] * inv[0], xs[c][1] * inv[1],
                        xs[c][2] * inv[2], xs[c][3] * inv[3]};
            __builtin_nontemporal_store(pv, (f32x4*)(op + (size_t)c * HW));
        }

        #pragma unroll
        for (int k = 0; k < 4; ++k) lsum += acc[k] / denom[k] - __logf(s[k]);
    }

    // wave-64 shuffle reduction -> LDS -> one atomic per block
    #pragma unroll
    for (int off = 32; off > 0; off >>= 1) lsum += __shfl_down(lsum, off);
    if ((threadIdx.x & 63) == 0) s_red[threadIdx.x >> 6] = lsum;
    __syncthreads();
    if (threadIdx.x == 0)
        atomicAdd(loss_acc, s_red[0] + s_red[1] + s_red[2] + s_red[3]);
}

__global__ void finalize_kernel(const float* __restrict__ acc, float* __restrict__ out) {
    out[0] = -acc[0] / (float)NPIX;
}

extern "C" void kernel_launch(void* const* d_in, const int* in_sizes, int n_in,
                              void* d_out, int out_size, void* d_ws, size_t ws_size,
                              hipStream_t stream) {
    const float* logits  = (const float*)d_in[0];
    const int*   targets = (const int*)d_in[1];
    const float* cm      = (const float*)d_in[2];
    float* out = (float*)d_out;
    float* ws  = (float*)d_ws;

    hipLaunchKernelGGL(ncm_kernel, dim3(1), dim3(64), 0, stream, cm, ws);

    hipLaunchKernelGGL(emloss_main, dim3(GRID), dim3(256), 0, stream,
                       logits, targets, ws, out, ws + 768);

    hipLaunchKernelGGL(finalize_kernel, dim3(1), dim3(1), 0, stream,
                       ws + 768, out + NPRED);
}

// Round 4
// 526.038 us; speedup vs baseline: 1.1826x; 1.1826x over previous
//
#include <hip/hip_runtime.h>

#define EPS 1e-8f

constexpr int B = 16, C = 19, H = 512, W = 512;
constexpr int HW = H * W;               // 262144 = 2^18
constexpr int NPIX = B * HW;            // 4194304
constexpr long long NPRED = (long long)B * C * HW;  // 79691776

typedef float f32x4 __attribute__((ext_vector_type(4)));

// ws layout (floats): [0..360] ncm (row-major [c][t]), [361..721] log(ncm+eps), [768] loss accumulator

__global__ void ncm_kernel(const float* __restrict__ cm, float* __restrict__ ws) {
    int t = threadIdx.x;
    if (t == 0) ws[768] = 0.0f;  // zero the loss accumulator (ws is poisoned each call)
    if (t < C) {
        float row[C];
        float m = -1e30f;
        #pragma unroll
        for (int j = 0; j < C; ++j) { row[j] = cm[t * C + j]; m = fmaxf(m, row[j]); }
        float s = 0.0f;
        #pragma unroll
        for (int j = 0; j < C; ++j) { row[j] = __expf(row[j] - m); s += row[j]; }
        float inv = 1.0f / s;
        #pragma unroll
        for (int j = 0; j < C; ++j) {
            float v = row[j] * inv;
            ws[t * C + j] = v;
            ws[361 + t * C + j] = __logf(v + EPS);
        }
    }
}

// One-shot 4096-block grid, 4 px/thread, float4, ALL accesses cached.
// Counter-backed decisions (do not revert):
//  - NO non-temporal stores: NT stores bypassed L2 write-coalescing
//    (WRITE_SIZE 319->653 MB, 2x amplification) AND streamed through L3,
//    wiping the cross-iteration logits residency (FETCH 164->348 MB).
//    Plain stores measured WRITE=312 MB and FETCH=164 MB (round 0).
//  - NO persistent grid-stride: 1024-block persistent version ran 4.0 TB/s
//    vs 6.4 TB/s for this one-shot shape (intra-wave iteration dependency
//    chain serializes; one-shot pipelines via block turnover).
// Loss algebra (unnormalized accumulation, one log per pixel):
//   loss_pix = [sum_c ncm*e*(lpre + (x-m))] / [sum_c ncm*e] - log(s)
__global__ __launch_bounds__(256, 4) void emloss_main(
        const float* __restrict__ logits,
        const int* __restrict__ targets,
        const float* __restrict__ ws,
        float* __restrict__ pred,
        float* __restrict__ loss_acc) {
    __shared__ float s_ncm[C * C];
    __shared__ float s_lpre[C * C];
    __shared__ float s_red[4];
    for (int i = threadIdx.x; i < C * C; i += blockDim.x) {
        s_ncm[i]  = ws[i];
        s_lpre[i] = ws[361 + i];
    }
    __syncthreads();

    int g = blockIdx.x * blockDim.x + threadIdx.x;  // one group of 4 consecutive pixels
    int pbase = g * 4;                               // grid exactly covers NPIX
    int b = pbase >> 18;                             // / HW
    int r = pbase & (HW - 1);
    const float* lp = logits + (size_t)b * C * HW + r;
    float*       op = pred   + (size_t)b * C * HW + r;

    // 19 classes x 4 pixels, coalesced 16 B/lane cached loads
    f32x4 xs[C];
    #pragma unroll
    for (int c = 0; c < C; ++c)
        xs[c] = *(const f32x4*)(lp + (size_t)c * HW);
    int4 tv = *(const int4*)(targets + pbase);
    int tt[4] = {tv.x, tv.y, tv.z, tv.w};

    float m[4] = {-1e30f, -1e30f, -1e30f, -1e30f};
    #pragma unroll
    for (int c = 0; c < C; ++c) {
        #pragma unroll
        for (int k = 0; k < 4; ++k) m[k] = fmaxf(m[k], xs[c][k]);
    }

    // single fused pass: exp, softmax denom, loss numerator/denominator
    float s[4]     = {0, 0, 0, 0};
    float denom[4] = {0, 0, 0, 0};
    float acc[4]   = {0, 0, 0, 0};
    #pragma unroll
    for (int c = 0; c < C; ++c) {
        #pragma unroll
        for (int k = 0; k < 4; ++k) {
            float d = xs[c][k] - m[k];
            float e = __expf(d);
            s[k] += e;
            float num = s_ncm[c * C + tt[k]] * e;
            denom[k] += num;
            acc[k]   += num * (s_lpre[c * C + tt[k]] + d);
            xs[c][k] = e;   // keep unnormalized exp for pred store
        }
    }

    float inv[4];
    #pragma unroll
    for (int k = 0; k < 4; ++k) inv[k] = 1.0f / s[k];
    #pragma unroll
    for (int c = 0; c < C; ++c) {
        f32x4 pv = {xs[c][0] * inv[0], xs[c][1] * inv[1],
                    xs[c][2] * inv[2], xs[c][3] * inv[3]};
        *(f32x4*)(op + (size_t)c * HW) = pv;
    }

    float lsum = 0.0f;
    #pragma unroll
    for (int k = 0; k < 4; ++k) lsum += acc[k] / denom[k] - __logf(s[k]);

    // wave-64 shuffle reduction -> LDS -> one atomic per block
    #pragma unroll
    for (int off = 32; off > 0; off >>= 1) lsum += __shfl_down(lsum, off);
    if ((threadIdx.x & 63) == 0) s_red[threadIdx.x >> 6] = lsum;
    __syncthreads();
    if (threadIdx.x == 0)
        atomicAdd(loss_acc, s_red[0] + s_red[1] + s_red[2] + s_red[3]);
}

__global__ void finalize_kernel(const float* __restrict__ acc, float* __restrict__ out) {
    out[0] = -acc[0] / (float)NPIX;
}

extern "C" void kernel_launch(void* const* d_in, const int* in_sizes, int n_in,
                              void* d_out, int out_size, void* d_ws, size_t ws_size,
                              hipStream_t stream) {
    const float* logits  = (const float*)d_in[0];
    const int*   targets = (const int*)d_in[1];
    const float* cm      = (const float*)d_in[2];
    float* out = (float*)d_out;
    float* ws  = (float*)d_ws;

    hipLaunchKernelGGL(ncm_kernel, dim3(1), dim3(64), 0, stream, cm, ws);

    int groups = NPIX / 4;            // 1048576
    int block = 256;
    int grid = groups / block;        // 4096
    hipLaunchKernelGGL(emloss_main, dim3(grid), dim3(block), 0, stream,
                       logits, targets, ws, out, ws + 768);

    hipLaunchKernelGGL(finalize_kernel, dim3(1), dim3(1), 0, stream,
                       ws + 768, out + NPRED);
}